// Round 11
// baseline (421.007 us; speedup 1.0000x reference)
//
#include <hip/hip_runtime.h>
#include <math.h>

// Problem constants (reference: N=256, H=512, K=2048, B=256, ETA=1.0)
#define NSEQ 256
#define HDIM 512
#define KDS  2048
#define BB   256
#define NM   255   // N-1 prefix rows

typedef __attribute__((ext_vector_type(8))) short bf16x8;
typedef __attribute__((ext_vector_type(4))) float f32x4;

#define AS1 __attribute__((address_space(1)))
#define AS3 __attribute__((address_space(3)))

// async global->LDS, 16B per lane; LDS dest = wave-uniform base + lane*16
__device__ __forceinline__ void gl16(const void* g, void* l) {
    __builtin_amdgcn_global_load_lds((AS1 const unsigned int*)g,
                                     (AS3 unsigned int*)l, 16, 0, 0);
}

// ---------------- workspace layout (float slots) ----------------
#define OFF_ACC   0            //        16
#define OFF_PMAX  16           // 2,088,960  per (m,b,32 k-groups) max
#define OFF_PSUM  2088976      // 2,088,960  sumexp
#define OFF_PARG  4177936      // 2,088,960  argmax (int)
#define OFF_PTGT  6266896      //    65,280  target logit per (m,b)
#define OFF_DSB   6332176      //   524,288 ushort = bf16 dataset [k][n]
#define OFF_SEQB  6594320      //    65,536 ushort = bf16 seq [b][j]
#define OFF_WBB   6627088      //   131,072 ushort = bf16 softmax(B_logits) [h][n]
#define OFF_PHI8  6692624      // 1,048,576 ushort = bf16 phi8 [h/8][k][8]
#define OFF_HATB  7216912      // 33,423,360 ushort = bf16 hat [m][b][h]
// end: 23,928,592 floats = 95.7 MB (< 140 MB proven available)

__device__ __forceinline__ ushort f2bf(float f) {
    unsigned u = __float_as_uint(f);
    unsigned r = (u + 0x7fffu + ((u >> 16) & 1u)) >> 16;   // RNE; NaN impossible here
    return (ushort)r;
}

__global__ void kzero(float* a) {
    if (threadIdx.x < 16) a[threadIdx.x] = 0.0f;
}

// convert dataset (K,N) and sequences (B,N) f32 -> bf16, same layouts
__global__ __launch_bounds__(256) void kernT2(const float* __restrict__ ds,
                                              const float* __restrict__ seq,
                                              ushort* __restrict__ dsb,
                                              ushort* __restrict__ seqb) {
    int id = blockIdx.x * 256 + threadIdx.x;      // grid covers KDS*NSEQ exactly
    dsb[id] = f2bf(ds[id]);
    if (id < BB * NSEQ) seqb[id] = f2bf(seq[id]);
}

// softmax each row of B_logits (512 x 256) -> bf16 wBb [h][n]
__global__ __launch_bounds__(256) void kernSB(const float* __restrict__ B_logits,
                                              ushort* __restrict__ wBb) {
    int w = threadIdx.x >> 6, l = threadIdx.x & 63;
    int h = blockIdx.x * 4 + w;
    float4 v = ((const float4*)(B_logits + (size_t)h * NSEQ))[l];
    float mx = fmaxf(fmaxf(v.x, v.y), fmaxf(v.z, v.w));
    #pragma unroll
    for (int off = 32; off; off >>= 1) mx = fmaxf(mx, __shfl_xor(mx, off));
    float e[4] = {__expf(v.x - mx), __expf(v.y - mx), __expf(v.z - mx), __expf(v.w - mx)};
    float s = e[0] + e[1] + e[2] + e[3];
    #pragma unroll
    for (int off = 32; off; off >>= 1) s += __shfl_xor(s, off);
    float inv = 1.0f / s;
    uint2 o;
    o.x = (unsigned)f2bf(e[0] * inv) | ((unsigned)f2bf(e[1] * inv) << 16);
    o.y = (unsigned)f2bf(e[2] * inv) | ((unsigned)f2bf(e[3] * inv) << 16);
    *(uint2*)(wBb + (size_t)h * NSEQ + l * 4) = o;
}

// phi GEMM: phi[k][h] = sum_n dsb[k][n] * wBb[h][n]; epilogue writes phi8 layout:
// phi8[(h>>3)*KDS*8 + k*8 + (h&7)] so kernD's B-fragment loads are 16B contiguous.
#define LDST 144
__global__ __launch_bounds__(256) void kernP(const ushort* __restrict__ dsb,
                                             const ushort* __restrict__ wBb,
                                             ushort* __restrict__ phi8) {
    int kblk = blockIdx.x, hblk = blockIdx.y;
    int t = threadIdx.x, lane = t & 63, wave = t >> 6;
    int bhalf = wave & 1, khalf = wave >> 1;
    __shared__ int4 Al4[128 * LDST / 16];
    __shared__ int4 Bl4[128 * LDST / 16];
    char* Al = (char*)Al4;
    char* Bl = (char*)Bl4;
    f32x4 acc[4][4];
    #pragma unroll
    for (int mb = 0; mb < 4; ++mb)
        #pragma unroll
        for (int nk = 0; nk < 4; ++nk) acc[mb][nk] = (f32x4){0.f, 0.f, 0.f, 0.f};
    const ushort* Abase = dsb + (size_t)kblk * 128 * NSEQ;
    const ushort* Bbase = wBb + (size_t)hblk * 128 * NSEQ;
    int l15 = lane & 15, lg = lane >> 4;
    for (int n0 = 0; n0 < NSEQ; n0 += 64) {
        #pragma unroll
        for (int i = 0; i < 4; ++i) {
            int c = i * 256 + t;
            int row = c >> 3, c8 = c & 7;
            int4 va = *(const int4*)(Abase + (size_t)row * NSEQ + n0 + c8 * 8);
            int4 vb = *(const int4*)(Bbase + (size_t)row * NSEQ + n0 + c8 * 8);
            *(int4*)(Al + row * LDST + c8 * 16) = va;
            *(int4*)(Bl + row * LDST + c8 * 16) = vb;
        }
        __syncthreads();
        #pragma unroll
        for (int ks = 0; ks < 2; ++ks) {
            bf16x8 fa[4], fb[4];
            #pragma unroll
            for (int mb = 0; mb < 4; ++mb)
                fa[mb] = *(const bf16x8*)(Al + (bhalf * 64 + mb * 16 + l15) * LDST + ks * 64 + lg * 16);
            #pragma unroll
            for (int nk = 0; nk < 4; ++nk)
                fb[nk] = *(const bf16x8*)(Bl + (khalf * 64 + nk * 16 + l15) * LDST + ks * 64 + lg * 16);
            #pragma unroll
            for (int mb = 0; mb < 4; ++mb)
                #pragma unroll
                for (int nk = 0; nk < 4; ++nk)
                    acc[mb][nk] = __builtin_amdgcn_mfma_f32_16x16x32_bf16(fa[mb], fb[nk], acc[mb][nk], 0, 0, 0);
        }
        __syncthreads();
    }
    #pragma unroll
    for (int mb = 0; mb < 4; ++mb)
        #pragma unroll
        for (int r = 0; r < 4; ++r) {
            int k = kblk * 128 + bhalf * 64 + mb * 16 + lg * 4 + r;
            #pragma unroll
            for (int nk = 0; nk < 4; ++nk) {
                int h = hblk * 128 + khalf * 64 + nk * 16 + l15;
                phi8[((size_t)(h >> 3) * KDS + k) * 8 + (h & 7)] = f2bf(acc[mb][nk][r]);
            }
        }
}

// Fused: masked softmax of A_logits[m+1, ht*128..+128, :] -> bf16 weights in LDS,
// then MFMA  hat[b][h] = sum_j seq[b][j] * W[h][j]  -> hatb bf16 [m][b][h].
__global__ __launch_bounds__(512) void kernC2(const float* __restrict__ A_logits,
                                              const ushort* __restrict__ seqb,
                                              ushort* __restrict__ hatb) {
    int m = blockIdx.x, ht = blockIdx.y;
    int t = threadIdx.x, lane = t & 63, wave = t >> 6;
    int bq = wave & 3, hhalf = wave >> 2;
    int l15 = lane & 15, lg = lane >> 4;
    __shared__ int4 Wl4[128 * 512 / 16];   // 64 KB
    char* Wl = (char*)Wl4;

    for (int rr = 0; rr < 16; ++rr) {
        int hl = wave + rr * 8;
        const float4* row = (const float4*)(A_logits + ((size_t)(m + 1) * HDIM + ht * 128 + hl) * NSEQ);
        float4 v = row[lane];
        int j0 = lane * 4;
        float x[4];
        x[0] = (j0 + 0 <= m) ? v.x : -INFINITY;
        x[1] = (j0 + 1 <= m) ? v.y : -INFINITY;
        x[2] = (j0 + 2 <= m) ? v.z : -INFINITY;
        x[3] = (j0 + 3 <= m) ? v.w : -INFINITY;
        float mx = fmaxf(fmaxf(x[0], x[1]), fmaxf(x[2], x[3]));
        #pragma unroll
        for (int off = 32; off; off >>= 1) mx = fmaxf(mx, __shfl_xor(mx, off));
        float e[4], s = 0.0f;
        #pragma unroll
        for (int q = 0; q < 4; ++q) {
            e[q] = (x[q] > -INFINITY) ? __expf(x[q] - mx) : 0.0f;
            s += e[q];
        }
        #pragma unroll
        for (int off = 32; off; off >>= 1) s += __shfl_xor(s, off);
        float inv = 1.0f / s;
        uint2 wv;
        wv.x = (unsigned)f2bf(e[0] * inv) | ((unsigned)f2bf(e[1] * inv) << 16);
        wv.y = (unsigned)f2bf(e[2] * inv) | ((unsigned)f2bf(e[3] * inv) << 16);
        int wo = (lane * 8) ^ ((hl & 7) << 4);
        *(uint2*)(Wl + hl * 512 + wo) = wv;
    }
    __syncthreads();

    f32x4 acc[4][4];
    #pragma unroll
    for (int mb = 0; mb < 4; ++mb)
        #pragma unroll
        for (int nk = 0; nk < 4; ++nk) acc[mb][nk] = (f32x4){0.f, 0.f, 0.f, 0.f};

    #pragma unroll
    for (int ks = 0; ks < 8; ++ks) {
        bf16x8 fa[4], fb[4];
        #pragma unroll
        for (int mb = 0; mb < 4; ++mb)
            fa[mb] = *(const bf16x8*)(seqb + (size_t)(bq * 64 + mb * 16 + l15) * NSEQ + ks * 32 + lg * 8);
        #pragma unroll
        for (int nk = 0; nk < 4; ++nk) {
            int hrow = hhalf * 64 + nk * 16 + l15;
            int co = (ks * 64 + lg * 16) ^ ((hrow & 7) << 4);
            fb[nk] = *(const bf16x8*)(Wl + hrow * 512 + co);
        }
        #pragma unroll
        for (int mb = 0; mb < 4; ++mb)
            #pragma unroll
            for (int nk = 0; nk < 4; ++nk)
                acc[mb][nk] = __builtin_amdgcn_mfma_f32_16x16x32_bf16(fa[mb], fb[nk], acc[mb][nk], 0, 0, 0);
    }

    #pragma unroll
    for (int mb = 0; mb < 4; ++mb)
        #pragma unroll
        for (int r = 0; r < 4; ++r) {
            int b = bq * 64 + mb * 16 + lg * 4 + r;
            #pragma unroll
            for (int nk = 0; nk < 4; ++nk) {
                int h = ht * 128 + hhalf * 64 + nk * 16 + l15;
                hatb[((size_t)m * BB + b) * HDIM + h] = f2bf(acc[mb][nk][r]);
            }
        }
}

// Logits GEMM, barrier-free (round-9 structure): A = 64 b-rows x 512 h in LDS
// (staged once, stride 1040B); B fragments from L2 via phi8 with a 2-DEEP
// register prefetch pipeline (3 named sets x/y/z, plain C loads -> compiler
// emits counted vmcnt). s_setprio(1) around each MFMA cluster.
__global__ __launch_bounds__(512, 4) void kernD(const ushort* __restrict__ hatb,
                                                const ushort* __restrict__ phi8,
                                                const int* __restrict__ indices,
                                                float* __restrict__ pmax,
                                                float* __restrict__ psum,
                                                int* __restrict__ parg,
                                                float* __restrict__ ptgt) {
    // XCD-chunked decode: 16 consecutive blocks (one m) per XCD position
    int id = blockIdx.x;                    // 0..4079
    int c = id & 7, pos = id >> 3;
    int lin = c * 510 + pos;                // bijective (4080 = 8*510)
    int m = lin >> 4, sub = lin & 15;
    int bblk = sub >> 2, kblk = sub & 3;

    int t = threadIdx.x, l = t & 63, w = t >> 6;   // w = k-slice index
    int l15 = l & 15, lg = l >> 4;

    __shared__ char Al[64 * 1040];          // 66,560 B
    __shared__ int idx_s[64];

    // one-time A stage: 64 rows x 1024B, linear source, padded-stride dest
    const char* Ab = (const char*)(hatb + ((size_t)m * BB + bblk * 64) * HDIM);
    #pragma unroll
    for (int i = 0; i < 8; ++i) {
        int row = w * 8 + i;
        gl16(Ab + (size_t)row * 1024 + l * 16, Al + row * 1040);
    }
    if (t < 64) idx_s[t] = indices[bblk * 64 + t];
    __syncthreads();

    int kb = kblk * 512 + w * 64;           // this wave's k base
    const ushort* Bp = phi8 + ((size_t)lg * KDS + kb + l15) * 8;
    const char* Ap = Al + l15 * 1040 + lg * 16;

    f32x4 acc[4][4];
    #pragma unroll
    for (int mb = 0; mb < 4; ++mb)
        #pragma unroll
        for (int nk = 0; nk < 4; ++nk) acc[mb][nk] = (f32x4){0.f, 0.f, 0.f, 0.f};

    bf16x8 x0, x1, x2, x3, y0, y1, y2, y3, z0, z1, z2, z3;

    // prologue: kstep 0 -> x set, kstep 1 -> y set (8 loads in flight)
    x0 = *(const bf16x8*)(Bp);
    x1 = *(const bf16x8*)(Bp + 128);
    x2 = *(const bf16x8*)(Bp + 256);
    x3 = *(const bf16x8*)(Bp + 384);
    {
        const ushort* p1 = Bp + 65536;
        y0 = *(const bf16x8*)(p1);
        y1 = *(const bf16x8*)(p1 + 128);
        y2 = *(const bf16x8*)(p1 + 256);
        y3 = *(const bf16x8*)(p1 + 384);
    }

#define DSTEP(K, C0, C1, C2, C3, N0, N1, N2, N3)                              \
    {                                                                         \
        if ((K) < 14) {                                                       \
            const ushort* p_ = Bp + (size_t)((K) + 2) * 65536;                \
            N0 = *(const bf16x8*)(p_);                                        \
            N1 = *(const bf16x8*)(p_ + 128);                                  \
            N2 = *(const bf16x8*)(p_ + 256);                                  \
            N3 = *(const bf16x8*)(p_ + 384);                                  \
        }                                                                     \
        bf16x8 fa0 = *(const bf16x8*)(Ap + 0 * 16640 + (K) * 64);             \
        bf16x8 fa1 = *(const bf16x8*)(Ap + 1 * 16640 + (K) * 64);             \
        bf16x8 fa2 = *(const bf16x8*)(Ap + 2 * 16640 + (K) * 64);             \
        bf16x8 fa3 = *(const bf16x8*)(Ap + 3 * 16640 + (K) * 64);             \
        __builtin_amdgcn_s_setprio(1);                                        \
        acc[0][0] = __builtin_amdgcn_mfma_f32_16x16x32_bf16(fa0, C0, acc[0][0], 0, 0, 0); \
        acc[0][1] = __builtin_amdgcn_mfma_f32_16x16x32_bf16(fa0, C1, acc[0][1], 0, 0, 0); \
        acc[0][2] = __builtin_amdgcn_mfma_f32_16x16x32_bf16(fa0, C2, acc[0][2], 0, 0, 0); \
        acc[0][3] = __builtin_amdgcn_mfma_f32_16x16x32_bf16(fa0, C3, acc[0][3], 0, 0, 0); \
        acc[1][0] = __builtin_amdgcn_mfma_f32_16x16x32_bf16(fa1, C0, acc[1][0], 0, 0, 0); \
        acc[1][1] = __builtin_amdgcn_mfma_f32_16x16x32_bf16(fa1, C1, acc[1][1], 0, 0, 0); \
        acc[1][2] = __builtin_amdgcn_mfma_f32_16x16x32_bf16(fa1, C2, acc[1][2], 0, 0, 0); \
        acc[1][3] = __builtin_amdgcn_mfma_f32_16x16x32_bf16(fa1, C3, acc[1][3], 0, 0, 0); \
        acc[2][0] = __builtin_amdgcn_mfma_f32_16x16x32_bf16(fa2, C0, acc[2][0], 0, 0, 0); \
        acc[2][1] = __builtin_amdgcn_mfma_f32_16x16x32_bf16(fa2, C1, acc[2][1], 0, 0, 0); \
        acc[2][2] = __builtin_amdgcn_mfma_f32_16x16x32_bf16(fa2, C2, acc[2][2], 0, 0, 0); \
        acc[2][3] = __builtin_amdgcn_mfma_f32_16x16x32_bf16(fa2, C3, acc[2][3], 0, 0, 0); \
        acc[3][0] = __builtin_amdgcn_mfma_f32_16x16x32_bf16(fa3, C0, acc[3][0], 0, 0, 0); \
        acc[3][1] = __builtin_amdgcn_mfma_f32_16x16x32_bf16(fa3, C1, acc[3][1], 0, 0, 0); \
        acc[3][2] = __builtin_amdgcn_mfma_f32_16x16x32_bf16(fa3, C2, acc[3][2], 0, 0, 0); \
        acc[3][3] = __builtin_amdgcn_mfma_f32_16x16x32_bf16(fa3, C3, acc[3][3], 0, 0, 0); \
        __builtin_amdgcn_s_setprio(0);                                        \
    }

    // use set K%3 (x=0,y=1,z=2); load into set (K+2)%3
    DSTEP(0,  x0, x1, x2, x3, z0, z1, z2, z3)
    DSTEP(1,  y0, y1, y2, y3, x0, x1, x2, x3)
    DSTEP(2,  z0, z1, z2, z3, y0, y1, y2, y3)
    DSTEP(3,  x0, x1, x2, x3, z0, z1, z2, z3)
    DSTEP(4,  y0, y1, y2, y3, x0, x1, x2, x3)
    DSTEP(5,  z0, z1, z2, z3, y0, y1, y2, y3)
    DSTEP(6,  x0, x1, x2, x3, z0, z1, z2, z3)
    DSTEP(7,  y0, y1, y2, y3, x0, x1, x2, x3)
    DSTEP(8,  z0, z1, z2, z3, y0, y1, y2, y3)
    DSTEP(9,  x0, x1, x2, x3, z0, z1, z2, z3)
    DSTEP(10, y0, y1, y2, y3, x0, x1, x2, x3)
    DSTEP(11, z0, z1, z2, z3, y0, y1, y2, y3)
    DSTEP(12, x0, x1, x2, x3, z0, z1, z2, z3)
    DSTEP(13, y0, y1, y2, y3, x0, x1, x2, x3)
    DSTEP(14, z0, z1, z2, z3, y0, y1, y2, y3)
    DSTEP(15, x0, x1, x2, x3, y0, y1, y2, y3)
#undef DSTEP

    // epilogue: per b-row, online (max, sumexp, argmax) over this wave's 64 k
    #pragma unroll
    for (int mb = 0; mb < 4; ++mb) {
        #pragma unroll
        for (int r = 0; r < 4; ++r) {
            int row_local = mb * 16 + lg * 4 + r;         // 0..63
            int bg = bblk * 64 + row_local;               // b 0..255
            int ib = idx_s[row_local];
            float M = -INFINITY, S = 0.0f;
            int KA = 0;
            #pragma unroll
            for (int nk = 0; nk < 4; ++nk) {
                float v = acc[mb][nk][r];
                int kg = kb + nk * 16 + l15;
                if (v > M) { S = S * __expf(M - v) + 1.0f; M = v; KA = kg; }
                else S += __expf(v - M);
                if (kg == ib) ptgt[m * BB + bg] = v;
            }
            #pragma unroll
            for (int off = 1; off < 16; off <<= 1) {
                float om = __shfl_xor(M, off);
                float os = __shfl_xor(S, off);
                int ok = __shfl_xor(KA, off);
                float Mn = fmaxf(M, om);
                S = S * __expf(M - Mn) + os * __expf(om - Mn);
                bool take = (om > M) || (om == M && ok < KA);
                KA = take ? ok : KA;
                M = Mn;
            }
            if (l15 == 0) {
                size_t pidx = ((size_t)m * BB + bg) * 32 + kblk * 8 + w;   // ascending k
                pmax[pidx] = M;
                psum[pidx] = S;
                parg[pidx] = KA;
            }
        }
    }
}

// combine 32 k-range partials per (m,b) -> CE + accuracy sums
__global__ __launch_bounds__(256) void kernE(const float* __restrict__ pmax,
                                             const float* __restrict__ psum,
                                             const int* __restrict__ parg,
                                             const float* __restrict__ ptgt,
                                             const int* __restrict__ indices,
                                             float* __restrict__ accum) {
    int m = blockIdx.x, b = threadIdx.x;
    size_t base = ((size_t)m * BB + b) * 32;
    float M = -INFINITY, S = 0.0f;
    int KA = 0;
    #pragma unroll 4
    for (int kb = 0; kb < 32; ++kb) {       // ascending k: strict > keeps first-index ties
        float om = pmax[base + kb], os = psum[base + kb];
        int ok = parg[base + kb];
        float Mn = fmaxf(M, om);
        S = S * __expf(M - Mn) + os * __expf(om - Mn);
        if (om > M) KA = ok;
        M = Mn;
    }
    float ce = M + logf(S) - ptgt[(size_t)m * BB + b];
    float corr = (KA == indices[b]) ? 1.0f : 0.0f;
    #pragma unroll
    for (int off = 32; off; off >>= 1) { ce += __shfl_xor(ce, off); corr += __shfl_xor(corr, off); }
    __shared__ float rc[4], rr[4];
    int wv = b >> 6;
    if ((b & 63) == 0) { rc[wv] = ce; rr[wv] = corr; }
    __syncthreads();
    if (b == 0) {
        atomicAdd(&accum[0], rc[0] + rc[1] + rc[2] + rc[3]);
        atomicAdd(&accum[1], rr[0] + rr[1] + rr[2] + rr[3]);
    }
}

__global__ void kfin(const float* __restrict__ accum, float* __restrict__ out) {
    if (threadIdx.x == 0) {
        const float inv = 1.0f / (255.0f * 256.0f);
        out[0] = accum[0] * inv;
        out[1] = accum[1] * inv;
    }
}

extern "C" void kernel_launch(void* const* d_in, const int* in_sizes, int n_in,
                              void* d_out, int out_size, void* d_ws, size_t ws_size,
                              hipStream_t stream) {
    const float* A_logits = (const float*)d_in[0];   // (256,512,256)
    const float* B_logits = (const float*)d_in[1];   // (512,256)
    const float* sequences = (const float*)d_in[2];  // (256,256)
    const float* dataset = (const float*)d_in[3];    // (2048,256)
    const int* indices = (const int*)d_in[4];        // (256,)
    float* out = (float*)d_out;

    float* ws = (float*)d_ws;
    float* accum = ws + OFF_ACC;
    float* pmax = ws + OFF_PMAX;
    float* psum = ws + OFF_PSUM;
    int* parg = (int*)(ws + OFF_PARG);
    float* ptgt = ws + OFF_PTGT;
    ushort* dsb = (ushort*)(ws + OFF_DSB);
    ushort* seqb = (ushort*)(ws + OFF_SEQB);
    ushort* wBb = (ushort*)(ws + OFF_WBB);
    ushort* phi8 = (ushort*)(ws + OFF_PHI8);
    ushort* hatb = (ushort*)(ws + OFF_HATB);

    kzero<<<1, 64, 0, stream>>>(accum);
    kernT2<<<(KDS * NSEQ) / 256, 256, 0, stream>>>(dataset, sequences, dsb, seqb);
    kernSB<<<HDIM / 4, 256, 0, stream>>>(B_logits, wBb);
    kernP<<<dim3(KDS / 128, HDIM / 128), 256, 0, stream>>>(dsb, wBb, phi8);
    kernC2<<<dim3(NM, HDIM / 128), 512, 0, stream>>>(A_logits, seqb, hatb);
    kernD<<<NM * 16, 512, 0, stream>>>(hatb, phi8, indices, pmax, psum, parg, ptgt);
    kernE<<<NM, 256, 0, stream>>>(pmax, psum, parg, ptgt, indices, accum);
    kfin<<<1, 64, 0, stream>>>(accum, out);
}

// Round 12
// 286.679 us; speedup vs baseline: 1.4686x; 1.4686x over previous
//
#include <hip/hip_runtime.h>
#include <math.h>

// Problem constants (reference: N=256, H=512, K=2048, B=256, ETA=1.0)
#define NSEQ 256
#define HDIM 512
#define KDS  2048
#define BB   256
#define NM   255   // N-1 prefix rows

typedef __attribute__((ext_vector_type(8))) short bf16x8;
typedef __attribute__((ext_vector_type(4))) float f32x4;

#define AS1 __attribute__((address_space(1)))
#define AS3 __attribute__((address_space(3)))

// async global->LDS, 16B per lane; LDS dest = wave-uniform base + lane*16
__device__ __forceinline__ void gl16(const void* g, void* l) {
    __builtin_amdgcn_global_load_lds((AS1 const unsigned int*)g,
                                     (AS3 unsigned int*)l, 16, 0, 0);
}

// ---------------- workspace layout (float slots) ----------------
#define OFF_ACC   0            //        16
#define OFF_PMAX  16           // 2,088,960  per (m,b,32 k-groups) max
#define OFF_PSUM  2088976      // 2,088,960  sumexp
#define OFF_PARG  4177936      // 2,088,960  argmax (int)
#define OFF_PTGT  6266896      //    65,280  target logit per (m,b)
#define OFF_DSB   6332176      //   524,288 ushort = bf16 dataset [k][n]
#define OFF_SEQB  6594320      //    65,536 ushort = bf16 seq [b][j]
#define OFF_WBB   6627088      //   131,072 ushort = bf16 softmax(B_logits) [h][n]
#define OFF_PHI8  6692624      // 1,048,576 ushort = bf16 phi8 [h/8][k][8]
#define OFF_HATB  7216912      // 33,423,360 ushort = bf16 hat [m][b][h]
// end: 23,928,592 floats = 95.7 MB (< 140 MB proven available)

__device__ __forceinline__ ushort f2bf(float f) {
    unsigned u = __float_as_uint(f);
    unsigned r = (u + 0x7fffu + ((u >> 16) & 1u)) >> 16;   // RNE; NaN impossible here
    return (ushort)r;
}

__global__ void kzero(float* a) {
    if (threadIdx.x < 16) a[threadIdx.x] = 0.0f;
}

// convert dataset (K,N) and sequences (B,N) f32 -> bf16, same layouts
__global__ __launch_bounds__(256) void kernT2(const float* __restrict__ ds,
                                              const float* __restrict__ seq,
                                              ushort* __restrict__ dsb,
                                              ushort* __restrict__ seqb) {
    int id = blockIdx.x * 256 + threadIdx.x;      // grid covers KDS*NSEQ exactly
    dsb[id] = f2bf(ds[id]);
    if (id < BB * NSEQ) seqb[id] = f2bf(seq[id]);
}

// softmax each row of B_logits (512 x 256) -> bf16 wBb [h][n]
__global__ __launch_bounds__(256) void kernSB(const float* __restrict__ B_logits,
                                              ushort* __restrict__ wBb) {
    int w = threadIdx.x >> 6, l = threadIdx.x & 63;
    int h = blockIdx.x * 4 + w;
    float4 v = ((const float4*)(B_logits + (size_t)h * NSEQ))[l];
    float mx = fmaxf(fmaxf(v.x, v.y), fmaxf(v.z, v.w));
    #pragma unroll
    for (int off = 32; off; off >>= 1) mx = fmaxf(mx, __shfl_xor(mx, off));
    float e[4] = {__expf(v.x - mx), __expf(v.y - mx), __expf(v.z - mx), __expf(v.w - mx)};
    float s = e[0] + e[1] + e[2] + e[3];
    #pragma unroll
    for (int off = 32; off; off >>= 1) s += __shfl_xor(s, off);
    float inv = 1.0f / s;
    uint2 o;
    o.x = (unsigned)f2bf(e[0] * inv) | ((unsigned)f2bf(e[1] * inv) << 16);
    o.y = (unsigned)f2bf(e[2] * inv) | ((unsigned)f2bf(e[3] * inv) << 16);
    *(uint2*)(wBb + (size_t)h * NSEQ + l * 4) = o;
}

// phi GEMM: phi[k][h] = sum_n dsb[k][n] * wBb[h][n]; epilogue writes phi8 layout:
// phi8[(h>>3)*KDS*8 + k*8 + (h&7)] so kernD's B-fragment loads are 16B contiguous.
#define LDST 144
__global__ __launch_bounds__(256) void kernP(const ushort* __restrict__ dsb,
                                             const ushort* __restrict__ wBb,
                                             ushort* __restrict__ phi8) {
    int kblk = blockIdx.x, hblk = blockIdx.y;
    int t = threadIdx.x, lane = t & 63, wave = t >> 6;
    int bhalf = wave & 1, khalf = wave >> 1;
    __shared__ int4 Al4[128 * LDST / 16];
    __shared__ int4 Bl4[128 * LDST / 16];
    char* Al = (char*)Al4;
    char* Bl = (char*)Bl4;
    f32x4 acc[4][4];
    #pragma unroll
    for (int mb = 0; mb < 4; ++mb)
        #pragma unroll
        for (int nk = 0; nk < 4; ++nk) acc[mb][nk] = (f32x4){0.f, 0.f, 0.f, 0.f};
    const ushort* Abase = dsb + (size_t)kblk * 128 * NSEQ;
    const ushort* Bbase = wBb + (size_t)hblk * 128 * NSEQ;
    int l15 = lane & 15, lg = lane >> 4;
    for (int n0 = 0; n0 < NSEQ; n0 += 64) {
        #pragma unroll
        for (int i = 0; i < 4; ++i) {
            int c = i * 256 + t;
            int row = c >> 3, c8 = c & 7;
            int4 va = *(const int4*)(Abase + (size_t)row * NSEQ + n0 + c8 * 8);
            int4 vb = *(const int4*)(Bbase + (size_t)row * NSEQ + n0 + c8 * 8);
            *(int4*)(Al + row * LDST + c8 * 16) = va;
            *(int4*)(Bl + row * LDST + c8 * 16) = vb;
        }
        __syncthreads();
        #pragma unroll
        for (int ks = 0; ks < 2; ++ks) {
            bf16x8 fa[4], fb[4];
            #pragma unroll
            for (int mb = 0; mb < 4; ++mb)
                fa[mb] = *(const bf16x8*)(Al + (bhalf * 64 + mb * 16 + l15) * LDST + ks * 64 + lg * 16);
            #pragma unroll
            for (int nk = 0; nk < 4; ++nk)
                fb[nk] = *(const bf16x8*)(Bl + (khalf * 64 + nk * 16 + l15) * LDST + ks * 64 + lg * 16);
            #pragma unroll
            for (int mb = 0; mb < 4; ++mb)
                #pragma unroll
                for (int nk = 0; nk < 4; ++nk)
                    acc[mb][nk] = __builtin_amdgcn_mfma_f32_16x16x32_bf16(fa[mb], fb[nk], acc[mb][nk], 0, 0, 0);
        }
        __syncthreads();
    }
    #pragma unroll
    for (int mb = 0; mb < 4; ++mb)
        #pragma unroll
        for (int r = 0; r < 4; ++r) {
            int k = kblk * 128 + bhalf * 64 + mb * 16 + lg * 4 + r;
            #pragma unroll
            for (int nk = 0; nk < 4; ++nk) {
                int h = hblk * 128 + khalf * 64 + nk * 16 + l15;
                phi8[((size_t)(h >> 3) * KDS + k) * 8 + (h & 7)] = f2bf(acc[mb][nk][r]);
            }
        }
}

// Fused: masked softmax of A_logits[m+1, ht*128..+128, :] -> bf16 weights in LDS,
// then MFMA  hat[b][h] = sum_j seq[b][j] * W[h][j]  -> hatb bf16 [m][b][h].
__global__ __launch_bounds__(512) void kernC2(const float* __restrict__ A_logits,
                                              const ushort* __restrict__ seqb,
                                              ushort* __restrict__ hatb) {
    int m = blockIdx.x, ht = blockIdx.y;
    int t = threadIdx.x, lane = t & 63, wave = t >> 6;
    int bq = wave & 3, hhalf = wave >> 2;
    int l15 = lane & 15, lg = lane >> 4;
    __shared__ int4 Wl4[128 * 512 / 16];   // 64 KB
    char* Wl = (char*)Wl4;

    for (int rr = 0; rr < 16; ++rr) {
        int hl = wave + rr * 8;
        const float4* row = (const float4*)(A_logits + ((size_t)(m + 1) * HDIM + ht * 128 + hl) * NSEQ);
        float4 v = row[lane];
        int j0 = lane * 4;
        float x[4];
        x[0] = (j0 + 0 <= m) ? v.x : -INFINITY;
        x[1] = (j0 + 1 <= m) ? v.y : -INFINITY;
        x[2] = (j0 + 2 <= m) ? v.z : -INFINITY;
        x[3] = (j0 + 3 <= m) ? v.w : -INFINITY;
        float mx = fmaxf(fmaxf(x[0], x[1]), fmaxf(x[2], x[3]));
        #pragma unroll
        for (int off = 32; off; off >>= 1) mx = fmaxf(mx, __shfl_xor(mx, off));
        float e[4], s = 0.0f;
        #pragma unroll
        for (int q = 0; q < 4; ++q) {
            e[q] = (x[q] > -INFINITY) ? __expf(x[q] - mx) : 0.0f;
            s += e[q];
        }
        #pragma unroll
        for (int off = 32; off; off >>= 1) s += __shfl_xor(s, off);
        float inv = 1.0f / s;
        uint2 wv;
        wv.x = (unsigned)f2bf(e[0] * inv) | ((unsigned)f2bf(e[1] * inv) << 16);
        wv.y = (unsigned)f2bf(e[2] * inv) | ((unsigned)f2bf(e[3] * inv) << 16);
        int wo = (lane * 8) ^ ((hl & 7) << 4);
        *(uint2*)(Wl + hl * 512 + wo) = wv;
    }
    __syncthreads();

    f32x4 acc[4][4];
    #pragma unroll
    for (int mb = 0; mb < 4; ++mb)
        #pragma unroll
        for (int nk = 0; nk < 4; ++nk) acc[mb][nk] = (f32x4){0.f, 0.f, 0.f, 0.f};

    #pragma unroll
    for (int ks = 0; ks < 8; ++ks) {
        bf16x8 fa[4], fb[4];
        #pragma unroll
        for (int mb = 0; mb < 4; ++mb)
            fa[mb] = *(const bf16x8*)(seqb + (size_t)(bq * 64 + mb * 16 + l15) * NSEQ + ks * 32 + lg * 8);
        #pragma unroll
        for (int nk = 0; nk < 4; ++nk) {
            int hrow = hhalf * 64 + nk * 16 + l15;
            int co = (ks * 64 + lg * 16) ^ ((hrow & 7) << 4);
            fb[nk] = *(const bf16x8*)(Wl + hrow * 512 + co);
        }
        #pragma unroll
        for (int mb = 0; mb < 4; ++mb)
            #pragma unroll
            for (int nk = 0; nk < 4; ++nk)
                acc[mb][nk] = __builtin_amdgcn_mfma_f32_16x16x32_bf16(fa[mb], fb[nk], acc[mb][nk], 0, 0, 0);
    }

    #pragma unroll
    for (int mb = 0; mb < 4; ++mb)
        #pragma unroll
        for (int r = 0; r < 4; ++r) {
            int b = bq * 64 + mb * 16 + lg * 4 + r;
            #pragma unroll
            for (int nk = 0; nk < 4; ++nk) {
                int h = ht * 128 + hhalf * 64 + nk * 16 + l15;
                hatb[((size_t)m * BB + b) * HDIM + h] = f2bf(acc[mb][nk][r]);
            }
        }
}

// Logits GEMM, barrier-free (round-9 main loop, verbatim): A = 64 b-rows x 512 h
// in LDS (staged once, stride 1040B); B fragments from L2 via phi8 with 1-deep
// x/y register prefetch (fits the 128-reg budget, no spill). NEW: two-pass
// epilogue (max -> sumexp, cndmask argmax, single-select ptgt) to cut VALU.
__global__ __launch_bounds__(512, 4) void kernD(const ushort* __restrict__ hatb,
                                                const ushort* __restrict__ phi8,
                                                const int* __restrict__ indices,
                                                float* __restrict__ pmax,
                                                float* __restrict__ psum,
                                                int* __restrict__ parg,
                                                float* __restrict__ ptgt) {
    // XCD-chunked decode: 16 consecutive blocks (one m) per XCD position
    int id = blockIdx.x;                    // 0..4079
    int c = id & 7, pos = id >> 3;
    int lin = c * 510 + pos;                // bijective (4080 = 8*510)
    int m = lin >> 4, sub = lin & 15;
    int bblk = sub >> 2, kblk = sub & 3;

    int t = threadIdx.x, l = t & 63, w = t >> 6;   // w = k-slice index
    int l15 = l & 15, lg = l >> 4;

    __shared__ char Al[64 * 1040];          // 66,560 B
    __shared__ int idx_s[64];

    // one-time A stage: 64 rows x 1024B, linear source, padded-stride dest
    const char* Ab = (const char*)(hatb + ((size_t)m * BB + bblk * 64) * HDIM);
    #pragma unroll
    for (int i = 0; i < 8; ++i) {
        int row = w * 8 + i;
        gl16(Ab + (size_t)row * 1024 + l * 16, Al + row * 1040);
    }
    if (t < 64) idx_s[t] = indices[bblk * 64 + t];
    __syncthreads();

    int kb = kblk * 512 + w * 64;           // this wave's k base
    const ushort* Bp = phi8 + ((size_t)lg * KDS + kb + l15) * 8;
    const char* Ap = Al + l15 * 1040 + lg * 16;

    f32x4 acc[4][4];
    #pragma unroll
    for (int mb = 0; mb < 4; ++mb)
        #pragma unroll
        for (int nk = 0; nk < 4; ++nk) acc[mb][nk] = (f32x4){0.f, 0.f, 0.f, 0.f};

    bf16x8 nb0 = *(const bf16x8*)(Bp);
    bf16x8 nb1 = *(const bf16x8*)(Bp + 128);
    bf16x8 nb2 = *(const bf16x8*)(Bp + 256);
    bf16x8 nb3 = *(const bf16x8*)(Bp + 384);

    #pragma unroll
    for (int kstep = 0; kstep < 16; ++kstep) {
        bf16x8 fb0 = nb0, fb1 = nb1, fb2 = nb2, fb3 = nb3;
        if (kstep < 15) {
            Bp += 65536;                    // 4*KDS*8 ushorts = 128 KB
            nb0 = *(const bf16x8*)(Bp);
            nb1 = *(const bf16x8*)(Bp + 128);
            nb2 = *(const bf16x8*)(Bp + 256);
            nb3 = *(const bf16x8*)(Bp + 384);
        }
        bf16x8 fa[4];
        #pragma unroll
        for (int mb = 0; mb < 4; ++mb)
            fa[mb] = *(const bf16x8*)(Ap + mb * 16640 + kstep * 64);   // 16*1040
        #pragma unroll
        for (int mb = 0; mb < 4; ++mb) {
            acc[mb][0] = __builtin_amdgcn_mfma_f32_16x16x32_bf16(fa[mb], fb0, acc[mb][0], 0, 0, 0);
            acc[mb][1] = __builtin_amdgcn_mfma_f32_16x16x32_bf16(fa[mb], fb1, acc[mb][1], 0, 0, 0);
            acc[mb][2] = __builtin_amdgcn_mfma_f32_16x16x32_bf16(fa[mb], fb2, acc[mb][2], 0, 0, 0);
            acc[mb][3] = __builtin_amdgcn_mfma_f32_16x16x32_bf16(fa[mb], fb3, acc[mb][3], 0, 0, 0);
        }
    }

    // epilogue v2: two-pass per b-row (max -> sumexp), cndmask argmax, 1 ptgt store
    #pragma unroll
    for (int mb = 0; mb < 4; ++mb) {
        #pragma unroll
        for (int r = 0; r < 4; ++r) {
            int row_local = mb * 16 + lg * 4 + r;         // 0..63
            int bg = bblk * 64 + row_local;               // b 0..255
            int ib = idx_s[row_local];
            float a0 = acc[mb][0][r], a1 = acc[mb][1][r];
            float a2 = acc[mb][2][r], a3 = acc[mb][3][r];
            // pass 1: row max over this wave's 64 k
            float M = fmaxf(fmaxf(a0, a1), fmaxf(a2, a3));
            #pragma unroll
            for (int off = 1; off < 16; off <<= 1) M = fmaxf(M, __shfl_xor(M, off));
            // pass 2: sum of exp (no rescale needed)
            float S = __expf(a0 - M) + __expf(a1 - M) + __expf(a2 - M) + __expf(a3 - M);
            #pragma unroll
            for (int off = 1; off < 16; off <<= 1) S += __shfl_xor(S, off);
            // argmax: min kg among exact-max matches (first-occurrence)
            int KA = 0x7fffffff;
            KA = (a3 == M) ? (kb + 48 + l15) : KA;
            KA = (a2 == M) ? (kb + 32 + l15) : KA;
            KA = (a1 == M) ? (kb + 16 + l15) : KA;
            KA = (a0 == M) ? (kb + l15) : KA;
            #pragma unroll
            for (int off = 1; off < 16; off <<= 1) {
                int ok = __shfl_xor(KA, off);
                KA = ok < KA ? ok : KA;
            }
            // target logit: single select + one exec-masked store
            int d = ib - kb;
            if ((unsigned)d < 64u && (d & 15) == l15) {
                float s0 = (d & 16) ? a1 : a0;
                float s1 = (d & 16) ? a3 : a2;
                ptgt[m * BB + bg] = (d & 32) ? s1 : s0;
            }
            if (l15 == 0) {
                size_t pidx = ((size_t)m * BB + bg) * 32 + kblk * 8 + w;   // ascending k
                pmax[pidx] = M;
                psum[pidx] = S;
                parg[pidx] = KA;
            }
        }
    }
}

// combine 32 k-range partials per (m,b) -> CE + accuracy sums
__global__ __launch_bounds__(256) void kernE(const float* __restrict__ pmax,
                                             const float* __restrict__ psum,
                                             const int* __restrict__ parg,
                                             const float* __restrict__ ptgt,
                                             const int* __restrict__ indices,
                                             float* __restrict__ accum) {
    int m = blockIdx.x, b = threadIdx.x;
    size_t base = ((size_t)m * BB + b) * 32;
    float M = -INFINITY, S = 0.0f;
    int KA = 0;
    #pragma unroll 4
    for (int kb = 0; kb < 32; ++kb) {       // ascending k: strict > keeps first-index ties
        float om = pmax[base + kb], os = psum[base + kb];
        int ok = parg[base + kb];
        float Mn = fmaxf(M, om);
        S = S * __expf(M - Mn) + os * __expf(om - Mn);
        if (om > M) KA = ok;
        M = Mn;
    }
    float ce = M + logf(S) - ptgt[(size_t)m * BB + b];
    float corr = (KA == indices[b]) ? 1.0f : 0.0f;
    #pragma unroll
    for (int off = 32; off; off >>= 1) { ce += __shfl_xor(ce, off); corr += __shfl_xor(corr, off); }
    __shared__ float rc[4], rr[4];
    int wv = b >> 6;
    if ((b & 63) == 0) { rc[wv] = ce; rr[wv] = corr; }
    __syncthreads();
    if (b == 0) {
        atomicAdd(&accum[0], rc[0] + rc[1] + rc[2] + rc[3]);
        atomicAdd(&accum[1], rr[0] + rr[1] + rr[2] + rr[3]);
    }
}

__global__ void kfin(const float* __restrict__ accum, float* __restrict__ out) {
    if (threadIdx.x == 0) {
        const float inv = 1.0f / (255.0f * 256.0f);
        out[0] = accum[0] * inv;
        out[1] = accum[1] * inv;
    }
}

extern "C" void kernel_launch(void* const* d_in, const int* in_sizes, int n_in,
                              void* d_out, int out_size, void* d_ws, size_t ws_size,
                              hipStream_t stream) {
    const float* A_logits = (const float*)d_in[0];   // (256,512,256)
    const float* B_logits = (const float*)d_in[1];   // (512,256)
    const float* sequences = (const float*)d_in[2];  // (256,256)
    const float* dataset = (const float*)d_in[3];    // (2048,256)
    const int* indices = (const int*)d_in[4];        // (256,)
    float* out = (float*)d_out;

    float* ws = (float*)d_ws;
    float* accum = ws + OFF_ACC;
    float* pmax = ws + OFF_PMAX;
    float* psum = ws + OFF_PSUM;
    int* parg = (int*)(ws + OFF_PARG);
    float* ptgt = ws + OFF_PTGT;
    ushort* dsb = (ushort*)(ws + OFF_DSB);
    ushort* seqb = (ushort*)(ws + OFF_SEQB);
    ushort* wBb = (ushort*)(ws + OFF_WBB);
    ushort* phi8 = (ushort*)(ws + OFF_PHI8);
    ushort* hatb = (ushort*)(ws + OFF_HATB);

    kzero<<<1, 64, 0, stream>>>(accum);
    kernT2<<<(KDS * NSEQ) / 256, 256, 0, stream>>>(dataset, sequences, dsb, seqb);
    kernSB<<<HDIM / 4, 256, 0, stream>>>(B_logits, wBb);
    kernP<<<dim3(KDS / 128, HDIM / 128), 256, 0, stream>>>(dsb, wBb, phi8);
    kernC2<<<dim3(NM, HDIM / 128), 512, 0, stream>>>(A_logits, seqb, hatb);
    kernD<<<NM * 16, 512, 0, stream>>>(hatb, phi8, indices, pmax, psum, parg, ptgt);
    kernE<<<NM, 256, 0, stream>>>(pmax, psum, parg, ptgt, indices, accum);
    kfin<<<1, 64, 0, stream>>>(accum, out);
}

// Round 13
// 285.999 us; speedup vs baseline: 1.4721x; 1.0024x over previous
//
#include <hip/hip_runtime.h>
#include <math.h>

// Problem constants (reference: N=256, H=512, K=2048, B=256, ETA=1.0)
#define NSEQ 256
#define HDIM 512
#define KDS  2048
#define BB   256
#define NM   255   // N-1 prefix rows

typedef __attribute__((ext_vector_type(8))) short bf16x8;
typedef __attribute__((ext_vector_type(4))) float f32x4;

#define AS1 __attribute__((address_space(1)))
#define AS3 __attribute__((address_space(3)))

// async global->LDS, 16B per lane; LDS dest = wave-uniform base + lane*16
__device__ __forceinline__ void gl16(const void* g, void* l) {
    __builtin_amdgcn_global_load_lds((AS1 const unsigned int*)g,
                                     (AS3 unsigned int*)l, 16, 0, 0);
}

// ---------------- workspace layout (float slots) ----------------
#define OFF_ACC   0            //        16
#define OFF_PMAX  16           // 2,088,960  per (m,b,32 k-groups) max
#define OFF_PSUM  2088976      // 2,088,960  sumexp
#define OFF_PARG  4177936      // 2,088,960  argmax (int)
#define OFF_PTGT  6266896      //    65,280  target logit per (m,b)
#define OFF_DSB   6332176      //   524,288 ushort = bf16 dataset [k][n]
#define OFF_SEQB  6594320      //    65,536 ushort = bf16 seq [b][j]
#define OFF_WBB   6627088      //   131,072 ushort = bf16 softmax(B_logits) [h][n]
#define OFF_PHI8  6692624      // 1,048,576 ushort = bf16 phi8 [h/8][k][8]
#define OFF_HATB  7216912      // 33,423,360 ushort = bf16 hat [m][b][h]
// end: 23,928,592 floats = 95.7 MB (< 140 MB proven available)

__device__ __forceinline__ ushort f2bf(float f) {
    unsigned u = __float_as_uint(f);
    unsigned r = (u + 0x7fffu + ((u >> 16) & 1u)) >> 16;   // RNE; NaN impossible here
    return (ushort)r;
}

__global__ void kzero(float* a) {
    if (threadIdx.x < 16) a[threadIdx.x] = 0.0f;
}

// convert dataset (K,N) and sequences (B,N) f32 -> bf16, same layouts
__global__ __launch_bounds__(256) void kernT2(const float* __restrict__ ds,
                                              const float* __restrict__ seq,
                                              ushort* __restrict__ dsb,
                                              ushort* __restrict__ seqb) {
    int id = blockIdx.x * 256 + threadIdx.x;      // grid covers KDS*NSEQ exactly
    dsb[id] = f2bf(ds[id]);
    if (id < BB * NSEQ) seqb[id] = f2bf(seq[id]);
}

// softmax each row of B_logits (512 x 256) -> bf16 wBb [h][n]
__global__ __launch_bounds__(256) void kernSB(const float* __restrict__ B_logits,
                                              ushort* __restrict__ wBb) {
    int w = threadIdx.x >> 6, l = threadIdx.x & 63;
    int h = blockIdx.x * 4 + w;
    float4 v = ((const float4*)(B_logits + (size_t)h * NSEQ))[l];
    float mx = fmaxf(fmaxf(v.x, v.y), fmaxf(v.z, v.w));
    #pragma unroll
    for (int off = 32; off; off >>= 1) mx = fmaxf(mx, __shfl_xor(mx, off));
    float e[4] = {__expf(v.x - mx), __expf(v.y - mx), __expf(v.z - mx), __expf(v.w - mx)};
    float s = e[0] + e[1] + e[2] + e[3];
    #pragma unroll
    for (int off = 32; off; off >>= 1) s += __shfl_xor(s, off);
    float inv = 1.0f / s;
    uint2 o;
    o.x = (unsigned)f2bf(e[0] * inv) | ((unsigned)f2bf(e[1] * inv) << 16);
    o.y = (unsigned)f2bf(e[2] * inv) | ((unsigned)f2bf(e[3] * inv) << 16);
    *(uint2*)(wBb + (size_t)h * NSEQ + l * 4) = o;
}

// phi GEMM: phi[k][h] = sum_n dsb[k][n] * wBb[h][n]; epilogue writes phi8 layout:
// phi8[(h>>3)*KDS*8 + k*8 + (h&7)] so kernD's B-fragment loads are 16B contiguous.
#define LDST 144
__global__ __launch_bounds__(256) void kernP(const ushort* __restrict__ dsb,
                                             const ushort* __restrict__ wBb,
                                             ushort* __restrict__ phi8) {
    int kblk = blockIdx.x, hblk = blockIdx.y;
    int t = threadIdx.x, lane = t & 63, wave = t >> 6;
    int bhalf = wave & 1, khalf = wave >> 1;
    __shared__ int4 Al4[128 * LDST / 16];
    __shared__ int4 Bl4[128 * LDST / 16];
    char* Al = (char*)Al4;
    char* Bl = (char*)Bl4;
    f32x4 acc[4][4];
    #pragma unroll
    for (int mb = 0; mb < 4; ++mb)
        #pragma unroll
        for (int nk = 0; nk < 4; ++nk) acc[mb][nk] = (f32x4){0.f, 0.f, 0.f, 0.f};
    const ushort* Abase = dsb + (size_t)kblk * 128 * NSEQ;
    const ushort* Bbase = wBb + (size_t)hblk * 128 * NSEQ;
    int l15 = lane & 15, lg = lane >> 4;
    for (int n0 = 0; n0 < NSEQ; n0 += 64) {
        #pragma unroll
        for (int i = 0; i < 4; ++i) {
            int c = i * 256 + t;
            int row = c >> 3, c8 = c & 7;
            int4 va = *(const int4*)(Abase + (size_t)row * NSEQ + n0 + c8 * 8);
            int4 vb = *(const int4*)(Bbase + (size_t)row * NSEQ + n0 + c8 * 8);
            *(int4*)(Al + row * LDST + c8 * 16) = va;
            *(int4*)(Bl + row * LDST + c8 * 16) = vb;
        }
        __syncthreads();
        #pragma unroll
        for (int ks = 0; ks < 2; ++ks) {
            bf16x8 fa[4], fb[4];
            #pragma unroll
            for (int mb = 0; mb < 4; ++mb)
                fa[mb] = *(const bf16x8*)(Al + (bhalf * 64 + mb * 16 + l15) * LDST + ks * 64 + lg * 16);
            #pragma unroll
            for (int nk = 0; nk < 4; ++nk)
                fb[nk] = *(const bf16x8*)(Bl + (khalf * 64 + nk * 16 + l15) * LDST + ks * 64 + lg * 16);
            #pragma unroll
            for (int mb = 0; mb < 4; ++mb)
                #pragma unroll
                for (int nk = 0; nk < 4; ++nk)
                    acc[mb][nk] = __builtin_amdgcn_mfma_f32_16x16x32_bf16(fa[mb], fb[nk], acc[mb][nk], 0, 0, 0);
        }
        __syncthreads();
    }
    #pragma unroll
    for (int mb = 0; mb < 4; ++mb)
        #pragma unroll
        for (int r = 0; r < 4; ++r) {
            int k = kblk * 128 + bhalf * 64 + mb * 16 + lg * 4 + r;
            #pragma unroll
            for (int nk = 0; nk < 4; ++nk) {
                int h = hblk * 128 + khalf * 64 + nk * 16 + l15;
                phi8[((size_t)(h >> 3) * KDS + k) * 8 + (h & 7)] = f2bf(acc[mb][nk][r]);
            }
        }
}

// Fused: masked softmax of A_logits[m+1, ht*128..+128, :] -> bf16 weights in LDS,
// then MFMA  hat[b][h] = sum_j seq[b][j] * W[h][j]  -> hatb bf16 [m][b][h].
__global__ __launch_bounds__(512) void kernC2(const float* __restrict__ A_logits,
                                              const ushort* __restrict__ seqb,
                                              ushort* __restrict__ hatb) {
    int m = blockIdx.x, ht = blockIdx.y;
    int t = threadIdx.x, lane = t & 63, wave = t >> 6;
    int bq = wave & 3, hhalf = wave >> 2;
    int l15 = lane & 15, lg = lane >> 4;
    __shared__ int4 Wl4[128 * 512 / 16];   // 64 KB
    char* Wl = (char*)Wl4;

    for (int rr = 0; rr < 16; ++rr) {
        int hl = wave + rr * 8;
        const float4* row = (const float4*)(A_logits + ((size_t)(m + 1) * HDIM + ht * 128 + hl) * NSEQ);
        float4 v = row[lane];
        int j0 = lane * 4;
        float x[4];
        x[0] = (j0 + 0 <= m) ? v.x : -INFINITY;
        x[1] = (j0 + 1 <= m) ? v.y : -INFINITY;
        x[2] = (j0 + 2 <= m) ? v.z : -INFINITY;
        x[3] = (j0 + 3 <= m) ? v.w : -INFINITY;
        float mx = fmaxf(fmaxf(x[0], x[1]), fmaxf(x[2], x[3]));
        #pragma unroll
        for (int off = 32; off; off >>= 1) mx = fmaxf(mx, __shfl_xor(mx, off));
        float e[4], s = 0.0f;
        #pragma unroll
        for (int q = 0; q < 4; ++q) {
            e[q] = (x[q] > -INFINITY) ? __expf(x[q] - mx) : 0.0f;
            s += e[q];
        }
        #pragma unroll
        for (int off = 32; off; off >>= 1) s += __shfl_xor(s, off);
        float inv = 1.0f / s;
        uint2 wv;
        wv.x = (unsigned)f2bf(e[0] * inv) | ((unsigned)f2bf(e[1] * inv) << 16);
        wv.y = (unsigned)f2bf(e[2] * inv) | ((unsigned)f2bf(e[3] * inv) << 16);
        int wo = (lane * 8) ^ ((hl & 7) << 4);
        *(uint2*)(Wl + hl * 512 + wo) = wv;
    }
    __syncthreads();

    f32x4 acc[4][4];
    #pragma unroll
    for (int mb = 0; mb < 4; ++mb)
        #pragma unroll
        for (int nk = 0; nk < 4; ++nk) acc[mb][nk] = (f32x4){0.f, 0.f, 0.f, 0.f};

    #pragma unroll
    for (int ks = 0; ks < 8; ++ks) {
        bf16x8 fa[4], fb[4];
        #pragma unroll
        for (int mb = 0; mb < 4; ++mb)
            fa[mb] = *(const bf16x8*)(seqb + (size_t)(bq * 64 + mb * 16 + l15) * NSEQ + ks * 32 + lg * 8);
        #pragma unroll
        for (int nk = 0; nk < 4; ++nk) {
            int hrow = hhalf * 64 + nk * 16 + l15;
            int co = (ks * 64 + lg * 16) ^ ((hrow & 7) << 4);
            fb[nk] = *(const bf16x8*)(Wl + hrow * 512 + co);
        }
        #pragma unroll
        for (int mb = 0; mb < 4; ++mb)
            #pragma unroll
            for (int nk = 0; nk < 4; ++nk)
                acc[mb][nk] = __builtin_amdgcn_mfma_f32_16x16x32_bf16(fa[mb], fb[nk], acc[mb][nk], 0, 0, 0);
    }

    #pragma unroll
    for (int mb = 0; mb < 4; ++mb)
        #pragma unroll
        for (int r = 0; r < 4; ++r) {
            int b = bq * 64 + mb * 16 + lg * 4 + r;
            #pragma unroll
            for (int nk = 0; nk < 4; ++nk) {
                int h = ht * 128 + hhalf * 64 + nk * 16 + l15;
                hatb[((size_t)m * BB + b) * HDIM + h] = f2bf(acc[mb][nk][r]);
            }
        }
}

// Logits GEMM, barrier-free (round-9 main loop, verbatim): A = 64 b-rows x 512 h
// in LDS (staged once, stride 1040B); B fragments from L2 via phi8 with 1-deep
// x/y register prefetch. Epilogue v2 (two-pass max->sumexp, cndmask argmax) with
// sched_barrier(0) per iteration: caps live-range overlap -> no scratch spill.
__global__ __launch_bounds__(512, 4) void kernD(const ushort* __restrict__ hatb,
                                                const ushort* __restrict__ phi8,
                                                const int* __restrict__ indices,
                                                float* __restrict__ pmax,
                                                float* __restrict__ psum,
                                                int* __restrict__ parg,
                                                float* __restrict__ ptgt) {
    // XCD-chunked decode: 16 consecutive blocks (one m) per XCD position
    int id = blockIdx.x;                    // 0..4079
    int c = id & 7, pos = id >> 3;
    int lin = c * 510 + pos;                // bijective (4080 = 8*510)
    int m = lin >> 4, sub = lin & 15;
    int bblk = sub >> 2, kblk = sub & 3;

    int t = threadIdx.x, l = t & 63, w = t >> 6;   // w = k-slice index
    int l15 = l & 15, lg = l >> 4;

    __shared__ char Al[64 * 1040];          // 66,560 B
    __shared__ int idx_s[64];

    // one-time A stage: 64 rows x 1024B, linear source, padded-stride dest
    const char* Ab = (const char*)(hatb + ((size_t)m * BB + bblk * 64) * HDIM);
    #pragma unroll
    for (int i = 0; i < 8; ++i) {
        int row = w * 8 + i;
        gl16(Ab + (size_t)row * 1024 + l * 16, Al + row * 1040);
    }
    if (t < 64) idx_s[t] = indices[bblk * 64 + t];
    __syncthreads();

    int kb = kblk * 512 + w * 64;           // this wave's k base
    const ushort* Bp = phi8 + ((size_t)lg * KDS + kb + l15) * 8;
    const char* Ap = Al + l15 * 1040 + lg * 16;

    f32x4 acc[4][4];
    #pragma unroll
    for (int mb = 0; mb < 4; ++mb)
        #pragma unroll
        for (int nk = 0; nk < 4; ++nk) acc[mb][nk] = (f32x4){0.f, 0.f, 0.f, 0.f};

    bf16x8 nb0 = *(const bf16x8*)(Bp);
    bf16x8 nb1 = *(const bf16x8*)(Bp + 128);
    bf16x8 nb2 = *(const bf16x8*)(Bp + 256);
    bf16x8 nb3 = *(const bf16x8*)(Bp + 384);

    #pragma unroll
    for (int kstep = 0; kstep < 16; ++kstep) {
        bf16x8 fb0 = nb0, fb1 = nb1, fb2 = nb2, fb3 = nb3;
        if (kstep < 15) {
            Bp += 65536;                    // 4*KDS*8 ushorts = 128 KB
            nb0 = *(const bf16x8*)(Bp);
            nb1 = *(const bf16x8*)(Bp + 128);
            nb2 = *(const bf16x8*)(Bp + 256);
            nb3 = *(const bf16x8*)(Bp + 384);
        }
        bf16x8 fa[4];
        #pragma unroll
        for (int mb = 0; mb < 4; ++mb)
            fa[mb] = *(const bf16x8*)(Ap + mb * 16640 + kstep * 64);   // 16*1040
        #pragma unroll
        for (int mb = 0; mb < 4; ++mb) {
            acc[mb][0] = __builtin_amdgcn_mfma_f32_16x16x32_bf16(fa[mb], fb0, acc[mb][0], 0, 0, 0);
            acc[mb][1] = __builtin_amdgcn_mfma_f32_16x16x32_bf16(fa[mb], fb1, acc[mb][1], 0, 0, 0);
            acc[mb][2] = __builtin_amdgcn_mfma_f32_16x16x32_bf16(fa[mb], fb2, acc[mb][2], 0, 0, 0);
            acc[mb][3] = __builtin_amdgcn_mfma_f32_16x16x32_bf16(fa[mb], fb3, acc[mb][3], 0, 0, 0);
        }
    }

    // epilogue v2 + per-iteration sched_barrier: two-pass (max -> sumexp),
    // cndmask argmax, 1 ptgt store; no cross-iteration live-range overlap.
    #pragma unroll
    for (int mb = 0; mb < 4; ++mb) {
        #pragma unroll
        for (int r = 0; r < 4; ++r) {
            int row_local = mb * 16 + lg * 4 + r;         // 0..63
            int bg = bblk * 64 + row_local;               // b 0..255
            int ib = idx_s[row_local];
            float a0 = acc[mb][0][r], a1 = acc[mb][1][r];
            float a2 = acc[mb][2][r], a3 = acc[mb][3][r];
            // pass 1: row max over this wave's 64 k
            float M = fmaxf(fmaxf(a0, a1), fmaxf(a2, a3));
            #pragma unroll
            for (int off = 1; off < 16; off <<= 1) M = fmaxf(M, __shfl_xor(M, off));
            // pass 2: sum of exp (no rescale needed)
            float S = __expf(a0 - M) + __expf(a1 - M) + __expf(a2 - M) + __expf(a3 - M);
            #pragma unroll
            for (int off = 1; off < 16; off <<= 1) S += __shfl_xor(S, off);
            // argmax: min kg among exact-max matches (first-occurrence)
            int KA = 0x7fffffff;
            KA = (a3 == M) ? (kb + 48 + l15) : KA;
            KA = (a2 == M) ? (kb + 32 + l15) : KA;
            KA = (a1 == M) ? (kb + 16 + l15) : KA;
            KA = (a0 == M) ? (kb + l15) : KA;
            #pragma unroll
            for (int off = 1; off < 16; off <<= 1) {
                int ok = __shfl_xor(KA, off);
                KA = ok < KA ? ok : KA;
            }
            // target logit: single select + one exec-masked store
            int d = ib - kb;
            if ((unsigned)d < 64u && (d & 15) == l15) {
                float s0 = (d & 16) ? a1 : a0;
                float s1 = (d & 16) ? a3 : a2;
                ptgt[m * BB + bg] = (d & 32) ? s1 : s0;
            }
            if (l15 == 0) {
                size_t pidx = ((size_t)m * BB + bg) * 32 + kblk * 8 + w;   // ascending k
                pmax[pidx] = M;
                psum[pidx] = S;
                parg[pidx] = KA;
            }
            __builtin_amdgcn_sched_barrier(0);   // cap live ranges: no spill
        }
    }
}

// combine 32 k-range partials per (m,b) -> CE + accuracy sums
__global__ __launch_bounds__(256) void kernE(const float* __restrict__ pmax,
                                             const float* __restrict__ psum,
                                             const int* __restrict__ parg,
                                             const float* __restrict__ ptgt,
                                             const int* __restrict__ indices,
                                             float* __restrict__ accum) {
    int m = blockIdx.x, b = threadIdx.x;
    size_t base = ((size_t)m * BB + b) * 32;
    float M = -INFINITY, S = 0.0f;
    int KA = 0;
    #pragma unroll 4
    for (int kb = 0; kb < 32; ++kb) {       // ascending k: strict > keeps first-index ties
        float om = pmax[base + kb], os = psum[base + kb];
        int ok = parg[base + kb];
        float Mn = fmaxf(M, om);
        S = S * __expf(M - Mn) + os * __expf(om - Mn);
        if (om > M) KA = ok;
        M = Mn;
    }
    float ce = M + logf(S) - ptgt[(size_t)m * BB + b];
    float corr = (KA == indices[b]) ? 1.0f : 0.0f;
    #pragma unroll
    for (int off = 32; off; off >>= 1) { ce += __shfl_xor(ce, off); corr += __shfl_xor(corr, off); }
    __shared__ float rc[4], rr[4];
    int wv = b >> 6;
    if ((b & 63) == 0) { rc[wv] = ce; rr[wv] = corr; }
    __syncthreads();
    if (b == 0) {
        atomicAdd(&accum[0], rc[0] + rc[1] + rc[2] + rc[3]);
        atomicAdd(&accum[1], rr[0] + rr[1] + rr[2] + rr[3]);
    }
}

__global__ void kfin(const float* __restrict__ accum, float* __restrict__ out) {
    if (threadIdx.x == 0) {
        const float inv = 1.0f / (255.0f * 256.0f);
        out[0] = accum[0] * inv;
        out[1] = accum[1] * inv;
    }
}

extern "C" void kernel_launch(void* const* d_in, const int* in_sizes, int n_in,
                              void* d_out, int out_size, void* d_ws, size_t ws_size,
                              hipStream_t stream) {
    const float* A_logits = (const float*)d_in[0];   // (256,512,256)
    const float* B_logits = (const float*)d_in[1];   // (512,256)
    const float* sequences = (const float*)d_in[2];  // (256,256)
    const float* dataset = (const float*)d_in[3];    // (2048,256)
    const int* indices = (const int*)d_in[4];        // (256,)
    float* out = (float*)d_out;

    float* ws = (float*)d_ws;
    float* accum = ws + OFF_ACC;
    float* pmax = ws + OFF_PMAX;
    float* psum = ws + OFF_PSUM;
    int* parg = (int*)(ws + OFF_PARG);
    float* ptgt = ws + OFF_PTGT;
    ushort* dsb = (ushort*)(ws + OFF_DSB);
    ushort* seqb = (ushort*)(ws + OFF_SEQB);
    ushort* wBb = (ushort*)(ws + OFF_WBB);
    ushort* phi8 = (ushort*)(ws + OFF_PHI8);
    ushort* hatb = (ushort*)(ws + OFF_HATB);

    kzero<<<1, 64, 0, stream>>>(accum);
    kernT2<<<(KDS * NSEQ) / 256, 256, 0, stream>>>(dataset, sequences, dsb, seqb);
    kernSB<<<HDIM / 4, 256, 0, stream>>>(B_logits, wBb);
    kernP<<<dim3(KDS / 128, HDIM / 128), 256, 0, stream>>>(dsb, wBb, phi8);
    kernC2<<<dim3(NM, HDIM / 128), 512, 0, stream>>>(A_logits, seqb, hatb);
    kernD<<<NM * 16, 512, 0, stream>>>(hatb, phi8, indices, pmax, psum, parg, ptgt);
    kernE<<<NM, 256, 0, stream>>>(pmax, psum, parg, ptgt, indices, accum);
    kfin<<<1, 64, 0, stream>>>(accum, out);
}